// Round 6
// baseline (367.381 us; speedup 1.0000x reference)
//
#include <hip/hip_runtime.h>
#include <math.h>

#define BATCH 8
#define CCH 384
#define NPIX 4096
#define NHEADS 6
#define SZ ((size_t)BATCH * CCH * NPIX) // elements per (B,C,N) buffer

typedef __attribute__((ext_vector_type(8))) short short8;  // 8 bf16 = 4 VGPR
typedef __attribute__((ext_vector_type(4))) float f32x4;   // MFMA acc

__device__ __forceinline__ float elu1(float x) { return x > 0.f ? x + 1.f : expf(x); }

__device__ __forceinline__ unsigned short bf16_rne(float f) {
    unsigned u = __builtin_bit_cast(unsigned, f);
    u += 0x7FFFu + ((u >> 16) & 1u);
    return (unsigned short)(u >> 16);
}
__device__ __forceinline__ float bf16_f(unsigned short h) {
    return __builtin_bit_cast(float, ((unsigned)h) << 16);
}
__device__ __forceinline__ unsigned packsplit(float v) {
    unsigned short hi = bf16_rne(v);
    unsigned short lo = bf16_rne(v - bf16_f(hi));
    return ((unsigned)hi << 16) | (unsigned)lo;
}
// exact fp32 value represented by a packed u32 (hi+lo)
__device__ __forceinline__ float unpackf(unsigned u) {
    return __builtin_bit_cast(float, u & 0xFFFF0000u) +
           __builtin_bit_cast(float, u << 16);
}

// ---------------------------------------------------------------------------
// Pack x (fp32) -> u32 (bf16_hi<<16 | bf16_lo), elementwise, vectorized.
// ---------------------------------------------------------------------------
__global__ __launch_bounds__(256) void pack_x_kernel(
    const float* __restrict__ X, unsigned* __restrict__ Xp)
{
    size_t i = ((size_t)blockIdx.x * 256 + threadIdx.x) * 4;
    float4 v = *(const float4*)(X + i);
    uint4 o;
    o.x = packsplit(v.x); o.y = packsplit(v.y);
    o.z = packsplit(v.z); o.w = packsplit(v.w);
    *(uint4*)(Xp + i) = o;
}

// ---------------------------------------------------------------------------
// Trig table: T[f][pos] = (sin, cos) of pos * 10000^(-f/96), f in 0..95, pos 0..63
// ---------------------------------------------------------------------------
__global__ __launch_bounds__(256) void trig_kernel(float2* __restrict__ T)
{
    const float KC = 0.13841367062030680f; // log2(10000)/96
    int idx = blockIdx.x * 256 + threadIdx.x; // 0..6143
    int f = idx >> 6, pos = idx & 63;
    float ang = (float)pos * exp2f(-KC * (float)f);
    float s, c;
    sincosf(ang, &s, &c);
    T[idx] = make_float2(s, c);
}

// ---------------------------------------------------------------------------
// Pack W (q,k,v,fc) into MFMA A-fragment order, split hi/lo bf16.
// f-blocks: 0..23 q (rope-permuted rows), 24..47 k, 48..71 v, 72..95 fc.
// Wp[f*12288 + c*1024 + hilo*512 + lane*8 + j] = W[ch(f,lane&15)][c*32+(lane>>4)*8+j]
// ---------------------------------------------------------------------------
__global__ __launch_bounds__(256) void pack_w_kernel(
    const float* __restrict__ Wq, const float* __restrict__ Wk,
    const float* __restrict__ Wv, const float* __restrict__ Wfc,
    unsigned short* __restrict__ Wp)
{
    const int tid = threadIdx.x;
    const int lane = tid & 63;
    const int f = blockIdx.x * 4 + (tid >> 6); // 0..95
    const int rloc = lane & 15;
    const int ks = (lane >> 4) * 8;

    const float* Wsel;
    int ch;
    if (f < 72) {
        int which = f / 24;
        int r = (f % 24) * 16 + rloc;
        if (which < 2) {
            int u = r >> 1;
            int cu = (u < 96) ? u : u + 96;
            ch = cu + 96 * (r & 1);
        } else {
            ch = r;
        }
        Wsel = (which == 0) ? Wq : (which == 1) ? Wk : Wv;
    } else {
        ch = (f - 72) * 16 + rloc;
        Wsel = Wfc;
    }

    for (int c = 0; c < 12; ++c) {
        short8 hv, lv;
#pragma unroll
        for (int j = 0; j < 8; ++j) {
            float v = Wsel[(size_t)ch * CCH + c * 32 + ks + j];
            unsigned short h = bf16_rne(v);
            hv[j] = (short)h;
            lv[j] = (short)bf16_rne(v - bf16_f(h));
        }
        size_t off = (size_t)f * 12288 + (size_t)c * 1024 + (size_t)lane * 8;
        *(short8*)(Wp + off) = hv;
        *(short8*)(Wp + off + 512) = lv;
    }
}

// ---------------------------------------------------------------------------
// Split-bf16 MFMA GEMM body, packed-u32 input, global_load_lds staging,
// 2-phase double-buffered LDS (T3-minimum): stage(c+1) issued BEFORE the
// compute on c, one barrier per iter -> HBM latency hides under MFMA.
// LDS per buffer: linear u32 [32 k][128 col]; swizzle in SOURCE address
// (granule XOR P(r)) and READ address (granule XOR P(k)); verified
// conflict-free in round 5 (SQ_LDS_BANK_CONFLICT = 0).
// MODE 0: M=1152 (q,k,v stacked, q/k rows permuted), rope(table)+elu epilogue.
//         q written fp32; k,v written PACKED u32 (for MFMA kv_kernel / fc).
// MODE 1: M=384 (fc), bias epilogue, fp32 out.
// acc[i][jj][reg]: m = mt*64+i*16+(lane>>4)*4+reg, n = nblk*128+wn*64+jj*16+(lane&15)
// ---------------------------------------------------------------------------
template <int MODE>
__device__ __forceinline__ void gemm_body(
    const unsigned* __restrict__ Xin,
    const unsigned short* __restrict__ Wp,
    const float2* __restrict__ Ttab,
    const float* __restrict__ b0, const float* __restrict__ b1, const float* __restrict__ b2,
    float* __restrict__ Oq, unsigned* __restrict__ Ok, unsigned* __restrict__ Ov,
    float* __restrict__ Ofc)
{
    __shared__ unsigned Bs[2][32 * 128];

    const int tid = threadIdx.x;
    const int lane = tid & 63;
    const int wv = tid >> 6;
    const int wm = wv >> 1, wn = wv & 1;
    const int mt = blockIdx.y * 2 + wm;       // 64-row tile idx
    const int nblk = blockIdx.x;
    const int b = blockIdx.z;
    const int g = lane >> 4;                  // 0..3
    const int ln = lane & 15;

    f32x4 acc[4][4] = {};

    const unsigned short* wbase = Wp + (size_t)(mt * 4) * 12288 + (size_t)lane * 8;
    const unsigned* sbU = Xin + (size_t)b * CCH * NPIX + nblk * 128;
    const int r_lo = (lane >> 5);             // 0/1 within a 2-row call

    auto stage = [&](int c, int buf) {
#pragma unroll
        for (int t = 0; t < 4; ++t) {
            const int r = wv * 8 + t * 2 + r_lo;                 // k-row 0..31
            const int P = (r & 7) ^ (((r >> 3) & 1) << 2);
            const int cg = (lane & 31) ^ P;                      // source granule
            const unsigned* gsrc = sbU + (size_t)(c * 32 + r) * NPIX + 4 * cg;
            unsigned* ldst = &Bs[buf][wv * 1024 + t * 256];      // wave-uniform
            __builtin_amdgcn_global_load_lds(
                (const __attribute__((address_space(1))) unsigned*)gsrc,
                (__attribute__((address_space(3))) unsigned*)ldst, 16, 0, 0);
        }
    };

    stage(0, 0);

#pragma unroll 1
    for (int c = 0; c < 12; ++c) {
        __syncthreads();  // drains vmcnt -> buf[c&1] ready; prev reads done
        if (c < 11) stage(c + 1, (c + 1) & 1);
        const unsigned* Bcur = &Bs[c & 1][0];

        short8 ah[4], al[4];
#pragma unroll
        for (int i = 0; i < 4; ++i) {
            const unsigned short* p = wbase + (size_t)i * 12288 + c * 1024;
            ah[i] = *(const short8*)(p);
            al[i] = *(const short8*)(p + 512);
        }

#pragma unroll
        for (int jj = 0; jj < 4; ++jj) {
            const int colbase = wn * 64 + jj * 16 + ln;
            const int cg2 = colbase >> 2;
            const int cw = colbase & 3;
            short8 bh, bl;
#pragma unroll
            for (int j = 0; j < 8; ++j) {
                const int k = g * 8 + j;
                const int Pk = j ^ ((g & 1) << 2);   // (k&7)^(((k>>3)&1)<<2)
                unsigned uu = Bcur[k * 128 + ((cg2 ^ Pk) << 2) + cw];
                bh[j] = (short)(uu >> 16);
                bl[j] = (short)(uu & 0xFFFFu);
            }
#pragma unroll
            for (int i = 0; i < 4; ++i) {
                acc[i][jj] = __builtin_amdgcn_mfma_f32_16x16x32_bf16(ah[i], bh, acc[i][jj], 0, 0, 0);
                acc[i][jj] = __builtin_amdgcn_mfma_f32_16x16x32_bf16(ah[i], bl, acc[i][jj], 0, 0, 0);
                acc[i][jj] = __builtin_amdgcn_mfma_f32_16x16x32_bf16(al[i], bh, acc[i][jj], 0, 0, 0);
            }
        }
    }

    const int ncol0 = nblk * 128 + wn * 64 + ln;

    if (MODE == 1) {
#pragma unroll
        for (int i = 0; i < 4; ++i) {
            const int rowb = mt * 64 + i * 16 + g * 4;
#pragma unroll
            for (int r = 0; r < 4; ++r) {
                const int row = rowb + r;
                const float bias = b0[row];
                float* orow = Ofc + ((size_t)b * CCH + row) * NPIX;
#pragma unroll
                for (int jj = 0; jj < 4; ++jj)
                    orow[ncol0 + jj * 16] = acc[i][jj][r] + bias;
            }
        }
    } else {
        const int which = mt / 6;
        const int mloc = (mt % 6) * 64;
        const float* bsel = (which == 0) ? b0 : (which == 1) ? b1 : b2;
        if (which == 2) {
            // v: plain bias, PACKED u32 out
#pragma unroll
            for (int i = 0; i < 4; ++i) {
                const int rowb = mloc + i * 16 + g * 4;
#pragma unroll
                for (int r = 0; r < 4; ++r) {
                    const int row = rowb + r;
                    const float bias = bsel[row];
                    unsigned* orow = Ov + ((size_t)b * CCH + row) * NPIX;
#pragma unroll
                    for (int jj = 0; jj < 4; ++jj)
                        orow[ncol0 + jj * 16] = packsplit(acc[i][jj][r] + bias);
                }
            }
        } else {
            // q (fp32 out, pre-scaled) / k (packed u32 out), rope + elu
            const int posH = nblk * 2 + wn;                // n>>6, thread-constant
#pragma unroll
            for (int i = 0; i < 4; ++i) {
#pragma unroll
                for (int p = 0; p < 2; ++p) {
                    const int re = mloc + i * 16 + g * 4 + 2 * p; // even permuted row
                    const int u = re >> 1;
                    const bool isH = (u < 96);
                    const int cu = isH ? u : u + 96;
                    const int jA = isH ? (u >> 1) : ((u - 96) >> 1);
                    const float be = bsel[cu];
                    const float bo = bsel[cu + 96];
                    const size_t offE = ((size_t)b * CCH + cu) * NPIX;
                    const size_t offO = offE + (size_t)96 * NPIX;
                    const float2* Ta = Ttab + jA * 64;
                    const float2* Tb = Ttab + (jA + 48) * 64;
#pragma unroll
                    for (int jj = 0; jj < 4; ++jj) {
                        const int n = ncol0 + jj * 16;
                        const int pw = isH ? posH : (jj * 16 + ln); // n>>6 or n&63
                        const float2 fa = Ta[pw];
                        const float2 fb = Tb[pw];
                        const float te = acc[i][jj][2 * p] + be;
                        const float to = acc[i][jj][2 * p + 1] + bo;
                        const float ve = te * fa.y - to * fa.x;
                        const float vo = to * fb.y + te * fb.x;
                        if (which == 0) {
                            Oq[offE + n] = elu1(ve * 0.125f);
                            Oq[offO + n] = elu1(vo * 0.125f);
                        } else {
                            Ok[offE + n] = packsplit(elu1(ve));
                            Ok[offO + n] = packsplit(elu1(vo));
                        }
                    }
                }
            }
        }
    }
}

__global__ __launch_bounds__(256, 2) void qkv_gemm(
    const unsigned* __restrict__ Xin, const unsigned short* __restrict__ Wp,
    const float2* __restrict__ Ttab,
    const float* __restrict__ b0, const float* __restrict__ b1, const float* __restrict__ b2,
    float* __restrict__ Oq, unsigned* __restrict__ Ok, unsigned* __restrict__ Ov)
{
    gemm_body<0>(Xin, Wp, Ttab, b0, b1, b2, Oq, Ok, Ov, nullptr);
}

__global__ __launch_bounds__(256, 2) void fc_gemm(
    const unsigned* __restrict__ Xin, const unsigned short* __restrict__ Wp,
    const float2* __restrict__ Ttab,
    const float* __restrict__ b0, float* __restrict__ Ofc)
{
    gemm_body<1>(Xin, Wp, Ttab, b0, b0, b0, nullptr, nullptr, nullptr, Ofc);
}

// ---------------------------------------------------------------------------
// kv[bh][d][e] = sum_n k[d,n]*v[e,n];  ksum[bh][d] = sum_n k[d,n]
// MFMA version on PACKED u32 k,v (3-term split). grid (48, 8); 4 waves/block,
// wave covers 128 n. Frag conventions identical to the verified GEMM:
// A: lane&15 -> d-row, slots g*8+j -> n;  B: lane&15 -> e-col, same slot map
// (operand slot permutations cancel). C: row d = g*4+reg, col e = lane&15.
// Cross-wave reduce in LDS, then one coalesced global-atomic pass per block.
// ---------------------------------------------------------------------------
__global__ __launch_bounds__(256) void kv_kernel(
    const unsigned* __restrict__ Kp, const unsigned* __restrict__ Vp,
    float* __restrict__ KV, float* __restrict__ KS)
{
    __shared__ float red[4096];
    const int tid = threadIdx.x;
    const int lane = tid & 63;
    const int wv = tid >> 6;
    const int bh = blockIdx.x;
    const int b = bh / NHEADS, h = bh % NHEADS;
    const int ln = lane & 15, g = lane >> 4;
    const int n0 = blockIdx.y * 512 + wv * 128;

    const unsigned* kb = Kp + ((size_t)b * CCH + h * 64) * NPIX + n0 + g * 8;
    const unsigned* vb = Vp + ((size_t)b * CCH + h * 64) * NPIX + n0 + g * 8;

    for (int t = tid; t < 4096; t += 256) red[t] = 0.f;

    f32x4 acc[4][4] = {};
    float ksl[4] = {0.f, 0.f, 0.f, 0.f};

#pragma unroll 1
    for (int s = 0; s < 4; ++s) {
        short8 kh[4], kl[4];
#pragma unroll
        for (int i = 0; i < 4; ++i) {
            const unsigned* src = kb + (size_t)(i * 16 + ln) * NPIX + s * 32;
            uint4 a0 = *(const uint4*)src;
            uint4 a1 = *(const uint4*)(src + 4);
            unsigned uu[8] = {a0.x, a0.y, a0.z, a0.w, a1.x, a1.y, a1.z, a1.w};
#pragma unroll
            for (int j = 0; j < 8; ++j) {
                kh[i][j] = (short)(uu[j] >> 16);
                kl[i][j] = (short)(uu[j] & 0xFFFFu);
                ksl[i] += unpackf(uu[j]);
            }
        }
#pragma unroll
        for (int j4 = 0; j4 < 4; ++j4) {
            const unsigned* src = vb + (size_t)(j4 * 16 + ln) * NPIX + s * 32;
            uint4 a0 = *(const uint4*)src;
            uint4 a1 = *(const uint4*)(src + 4);
            unsigned uu[8] = {a0.x, a0.y, a0.z, a0.w, a1.x, a1.y, a1.z, a1.w};
            short8 vh, vl;
#pragma unroll
            for (int j = 0; j < 8; ++j) {
                vh[j] = (short)(uu[j] >> 16);
                vl[j] = (short)(uu[j] & 0xFFFFu);
            }
#pragma unroll
            for (int i = 0; i < 4; ++i) {
                acc[i][j4] = __builtin_amdgcn_mfma_f32_16x16x32_bf16(kh[i], vh, acc[i][j4], 0, 0, 0);
                acc[i][j4] = __builtin_amdgcn_mfma_f32_16x16x32_bf16(kh[i], vl, acc[i][j4], 0, 0, 0);
                acc[i][j4] = __builtin_amdgcn_mfma_f32_16x16x32_bf16(kl[i], vh, acc[i][j4], 0, 0, 0);
            }
        }
    }

    // ksum: reduce across the 4 g-groups (lanes ln, ln+16, ln+32, ln+48)
#pragma unroll
    for (int i = 0; i < 4; ++i) {
        float v2 = ksl[i];
        v2 += __shfl_xor(v2, 16);
        v2 += __shfl_xor(v2, 32);
        if (g == 0) atomicAdd(&KS[bh * 64 + i * 16 + ln], v2);
    }

    // cross-wave kv reduce in LDS, then per-block global atomics
    __syncthreads();
#pragma unroll
    for (int i = 0; i < 4; ++i)
#pragma unroll
        for (int j4 = 0; j4 < 4; ++j4)
#pragma unroll
            for (int r = 0; r < 4; ++r)
                atomicAdd(&red[(i * 16 + g * 4 + r) * 64 + j4 * 16 + ln], acc[i][j4][r]);
    __syncthreads();
    float* kvb = KV + (size_t)bh * 4096;
    for (int t = tid; t < 4096; t += 256) atomicAdd(&kvb[t], red[t]);
}

// ---------------------------------------------------------------------------
// out[b,64h+e,n] = (sum_d q*kv) / (sum_d q*ksum + 1e-6), written PACKED u32.
// ---------------------------------------------------------------------------
__global__ __launch_bounds__(256) void attn_kernel(
    const float* __restrict__ Q, const float* __restrict__ KV,
    const float* __restrict__ KS, unsigned* __restrict__ O)
{
    __shared__ float Qs[64][132];
    __shared__ float KVs[64][64];
    __shared__ float KSs[64];
    const int tid = threadIdx.x;
    const int n0 = blockIdx.x * 128;
    const int bh = blockIdx.y;
    const int b = bh / NHEADS, h = bh % NHEADS;
    const float* qb = Q + ((size_t)b * CCH + h * 64) * NPIX;

    {
        const int row = tid >> 2;
        const int c0 = (tid & 3) * 32;
        const float* qr = qb + (size_t)row * NPIX + n0 + c0;
#pragma unroll
        for (int j = 0; j < 8; ++j)
            *(float4*)&Qs[row][c0 + j * 4] = *(const float4*)&qr[j * 4];
        const int kc = (tid & 3) * 16;
        const float* kvr = KV + (size_t)bh * 4096 + (size_t)row * 64 + kc;
#pragma unroll
        for (int j = 0; j < 4; ++j)
            *(float4*)&KVs[row][kc + j * 4] = *(const float4*)&kvr[j * 4];
        if (tid < 64) KSs[tid] = KS[bh * 64 + tid];
    }
    __syncthreads();

    const int tx = tid & 31;
    const int ty = tid >> 5;
    float acc[8][4];
    float accn[4] = {0.f, 0.f, 0.f, 0.f};
#pragma unroll
    for (int r = 0; r < 8; ++r)
#pragma unroll
        for (int j = 0; j < 4; ++j) acc[r][j] = 0.f;

#pragma unroll 8
    for (int d = 0; d < 64; ++d) {
        float4 qv = *(const float4*)&Qs[d][tx * 4];
        float qa[4] = {qv.x, qv.y, qv.z, qv.w};
        float ksv = KSs[d];
#pragma unroll
        for (int j = 0; j < 4; ++j) accn[j] += ksv * qa[j];
        float4 k0 = *(const float4*)&KVs[d][ty * 8];
        float4 k1 = *(const float4*)&KVs[d][ty * 8 + 4];
        float kva[8] = {k0.x, k0.y, k0.z, k0.w, k1.x, k1.y, k1.z, k1.w};
#pragma unroll
        for (int r = 0; r < 8; ++r)
#pragma unroll
            for (int j = 0; j < 4; ++j) acc[r][j] += kva[r] * qa[j];
    }

    float rcp[4];
#pragma unroll
    for (int j = 0; j < 4; ++j) rcp[j] = 1.f / (accn[j] + 1e-6f);
#pragma unroll
    for (int r = 0; r < 8; ++r) {
        unsigned* orow = O + ((size_t)b * CCH + h * 64 + ty * 8 + r) * NPIX + n0 + tx * 4;
        uint4 o4;
        o4.x = packsplit(acc[r][0] * rcp[0]);
        o4.y = packsplit(acc[r][1] * rcp[1]);
        o4.z = packsplit(acc[r][2] * rcp[2]);
        o4.w = packsplit(acc[r][3] * rcp[3]);
        *(uint4*)orow = o4;
    }
}

__global__ void zero_kernel(float* p, int n)
{
    int i = blockIdx.x * blockDim.x + threadIdx.x;
    if (i < n) p[i] = 0.f;
}

extern "C" void kernel_launch(void* const* d_in, const int* in_sizes, int n_in,
                              void* d_out, int out_size, void* d_ws, size_t ws_size,
                              hipStream_t stream)
{
    const float* x   = (const float*)d_in[0];
    const float* Wq  = (const float*)d_in[1];
    const float* bq  = (const float*)d_in[2];
    const float* Wk  = (const float*)d_in[3];
    const float* bk  = (const float*)d_in[4];
    const float* Wv  = (const float*)d_in[5];
    const float* bv  = (const float*)d_in[6];
    const float* Wfc = (const float*)d_in[7];
    const float* bfc = (const float*)d_in[8];
    float* out = (float*)d_out;
    float* ws = (float*)d_ws;

    float*    q  = ws;                   // (B,C,N) fp32 post-rope/elu/scale
    unsigned* kp = (unsigned*)(ws + SZ); // (B,C,N) packed k; later attn PACKED out
    unsigned* vp = (unsigned*)(ws + 2 * SZ); // (B,C,N) packed v
    float* kv    = ws + 3 * SZ;          // (48,64,64)
    float* ksum  = kv + 48 * 64 * 64;    // (48,64)
    float2* Ttab = (float2*)(ksum + 48 * 64);               // 96*64 float2 (48KB)
    unsigned short* Wp = (unsigned short*)(Ttab + 96 * 64); // 96*12288 ushorts
    unsigned* xp = (unsigned*)d_out;     // packed x aliases d_out (dead until FC)
    unsigned* op = kp;                   // packed attn output overwrites dead kp

    const int nz = 48 * 64 * 64 + 48 * 64;
    zero_kernel<<<(nz + 255) / 256, 256, 0, stream>>>(kv, nz);
    trig_kernel<<<24, 256, 0, stream>>>(Ttab);
    pack_w_kernel<<<24, 256, 0, stream>>>(Wq, Wk, Wv, Wfc, Wp);
    pack_x_kernel<<<(int)(SZ / 1024), 256, 0, stream>>>(x, xp);
    qkv_gemm<<<dim3(32, 9, BATCH), 256, 0, stream>>>(xp, Wp, Ttab, bq, bk, bv, q, kp, vp);
    kv_kernel<<<dim3(48, 8), 256, 0, stream>>>(kp, vp, kv, ksum);
    attn_kernel<<<dim3(32, 48), 256, 0, stream>>>(q, kv, ksum, op);
    fc_gemm<<<dim3(32, 3, BATCH), 256, 0, stream>>>(op, Wp + (size_t)72 * 12288, Ttab,
                                                    bfc, out);
}